// Round 3
// baseline (992.344 us; speedup 1.0000x reference)
//
#include <hip/hip_runtime.h>
#include <hip/hip_fp16.h>
#include <math.h>

// Problem constants
// B=8, T=16, IMG=128, CF=32, WO=HO=32, N=1024, M=32, DH=256
// conv SAME stride2: pad_lo=0, pad_hi=1  ->  in_idx = 2*out + k

#define TWOPI_32 0.19634954084936207f  // 2*pi/32

// ---------------- conv1: [img][3][128][128] -> [img][32][64][64], stride2 SAME, ReLU
__global__ __launch_bounds__(256) void conv1_kernel(const float* __restrict__ in,
                                                    const float* __restrict__ w,
                                                    const float* __restrict__ bias,
                                                    float* __restrict__ out)
{
    const int strip = blockIdx.x;   // 4 strips of 16 output rows
    const int img   = blockIdx.y;   // 128 images
    const int tid   = threadIdx.x;
    __shared__ float sIn[3*33*130];
    const int iy0 = strip * 32;
    for (int idx = tid; idx < 3*33*130; idx += 256) {
        int ic  = idx / (33*130);
        int rem = idx - ic*(33*130);
        int li  = rem / 130;
        int col = rem - li*130;
        int iy  = iy0 + li;
        float v = 0.f;
        if (iy < 128 && col < 128)
            v = in[(((size_t)img*3 + ic)*128 + iy)*128 + col];
        sIn[idx] = v;
    }
    __syncthreads();
    const int oy0 = strip*16;
    #pragma unroll
    for (int p = 0; p < 4; ++p) {
        int pos = p*256 + tid;       // 1024 positions: 16 rows x 64 cols
        int ly = pos >> 6;
        int ox = pos & 63;
        float r[27];
        #pragma unroll
        for (int ic = 0; ic < 3; ++ic)
            #pragma unroll
            for (int dy = 0; dy < 3; ++dy)
                #pragma unroll
                for (int dx = 0; dx < 3; ++dx)
                    r[(ic*3+dy)*3+dx] = sIn[ic*(33*130) + (2*ly+dy)*130 + 2*ox + dx];
        for (int oc = 0; oc < 32; ++oc) {
            float acc = bias[oc];
            #pragma unroll
            for (int q = 0; q < 27; ++q)
                acc += r[q] * w[oc*27 + q];
            out[(((size_t)img*32 + oc)*64 + (oy0+ly))*64 + ox] = fmaxf(acc, 0.f);
        }
    }
}

// ---------------- conv2: [img][32][64][64] -> [img][32][32][32], stride2 SAME, ReLU
__global__ __launch_bounds__(256) void conv2_kernel(const float* __restrict__ in,
                                                    const float* __restrict__ w,
                                                    const float* __restrict__ bias,
                                                    float* __restrict__ out)
{
    const int strip = blockIdx.x;   // 8 strips of 4 output rows
    const int img   = blockIdx.y;
    const int tid   = threadIdx.x;
    __shared__ float sIn[32*9*66];
    const int iy0 = strip*8;
    for (int idx = tid; idx < 32*9*66; idx += 256) {
        int ic  = idx / (9*66);
        int rem = idx - ic*(9*66);
        int li  = rem / 66;
        int col = rem - li*66;
        int iy  = iy0 + li;
        float v = 0.f;
        if (iy < 64 && col < 64)
            v = in[(((size_t)img*32 + ic)*64 + iy)*64 + col];
        sIn[idx] = v;
    }
    __syncthreads();
    const int posl = tid & 127;     // 128 positions: 4 rows x 32 cols
    const int half = tid >> 7;      // 2 halves of 16 out-channels
    const int ly = posl >> 5;
    const int ox = posl & 31;
    float acc[16];
    #pragma unroll
    for (int j = 0; j < 16; ++j) acc[j] = 0.f;
    for (int ic = 0; ic < 32; ++ic) {
        float r[9];
        #pragma unroll
        for (int dy = 0; dy < 3; ++dy)
            #pragma unroll
            for (int dx = 0; dx < 3; ++dx)
                r[dy*3+dx] = sIn[ic*(9*66) + (2*ly+dy)*66 + 2*ox + dx];
        #pragma unroll
        for (int j = 0; j < 16; ++j) {
            int oc = half*16 + j;
            const float* wp = &w[(oc*32 + ic)*9];
            float a = acc[j];
            #pragma unroll
            for (int q = 0; q < 9; ++q) a += r[q]*wp[q];
            acc[j] = a;
        }
    }
    const int oy = strip*4 + ly;
    #pragma unroll
    for (int j = 0; j < 16; ++j) {
        int oc = half*16 + j;
        out[(((size_t)img*32 + oc)*32 + oy)*32 + ox] = fmaxf(acc[j] + bias[oc], 0.f);
    }
}

// ---------------- xhalf: transpose xfeat [bt][m][n] f32 -> xh [bt][n][m] f16
__global__ __launch_bounds__(256) void xhalf_kernel(const float* __restrict__ xf,
                                                    __half* __restrict__ xh)
{
    const int bt  = blockIdx.x;
    const int tid = threadIdx.x;
    __shared__ float sT[32][257];
    const float* src = xf + (size_t)bt*32768;
    __half* dst = xh + (size_t)bt*32768;
    for (int tt = 0; tt < 4; ++tt) {
        #pragma unroll
        for (int m = 0; m < 32; ++m)
            sT[m][tid] = src[m*1024 + tt*256 + tid];
        __syncthreads();
        uint4 o[4];
        unsigned int* ou = (unsigned int*)o;
        #pragma unroll
        for (int k = 0; k < 16; ++k) {
            __half2 h2 = __floats2half2_rn(sT[2*k][tid], sT[2*k+1][tid]);
            ou[k] = *(unsigned int*)&h2;
        }
        uint4* dp = (uint4*)(dst + (size_t)(tt*256 + tid)*32);
        dp[0] = o[0]; dp[1] = o[1]; dp[2] = o[2]; dp[3] = o[3];
        __syncthreads();
    }
}

// ---------------- xmean: mean over n of xfeat rows [(bt*32+m)][1024]
__global__ __launch_bounds__(256) void xmean_kernel(const float* __restrict__ xfeat,
                                                    float* __restrict__ xmean)
{
    const int row  = blockIdx.x*4 + (threadIdx.x >> 6);   // 4096 rows
    const int lane = threadIdx.x & 63;
    const float* p = xfeat + (size_t)row*1024;
    float s = 0.f;
    #pragma unroll
    for (int jj = 0; jj < 16; ++jj) s += p[lane + 64*jj];
    #pragma unroll
    for (int d = 32; d > 0; d >>= 1) s += __shfl_xor(s, d, 64);
    if (lane == 0) xmean[row] = s * (1.f/1024.f);
}

// ---------------- NTM scalar recurrence: one block per batch, 512 threads.
// Emits only: w_t[n] (wbuf), e/a/g (eag), layernorm stats (lnst).
// c lives entirely in registers; x read from pre-transposed f16 copy.
__global__ __attribute__((amdgpu_flat_work_group_size(512,512), amdgpu_waves_per_eu(2,2)))
void ntm_scal_kernel(
    const float* __restrict__ xfeat, const __half* __restrict__ xh,
    const float* __restrict__ xmean,
    const float* __restrict__ Wk, const float* __restrict__ bk,
    const float* __restrict__ Wbeta, const float* __restrict__ bbeta,
    const float* __restrict__ Wh, const float* __restrict__ bh,
    const float* __restrict__ We, const float* __restrict__ Wa,
    const float* __restrict__ Wg,
    float* __restrict__ wbuf, float* __restrict__ eag, float* __restrict__ lnst)
{
    const int b    = blockIdx.x;
    const int tid  = threadIdx.x;
    const int lane = tid & 63;
    const int wid  = tid >> 6;

    __shared__ float sWk[8192];   // [m][j] 32x256
    __shared__ float sWe[8192];
    __shared__ float sWa[8192];
    __shared__ float sH[256];
    __shared__ float sBh[256];
    __shared__ __align__(16) float sInp[320];
    __shared__ __align__(16) float sK[32];
    __shared__ float sE[32];
    __shared__ float sA[32];
    __shared__ float sBk[32];
    __shared__ float sXm[512];
    __shared__ float sRedC[256];
    __shared__ float sRedB[4];
    __shared__ float sRedG[4];
    __shared__ float sRedD[8];
    __shared__ float sRedL[16];

    // stage small weights to LDS
    for (int i = tid; i < 8192; i += 512) {
        sWk[i] = Wk[i]; sWe[i] = We[i]; sWa[i] = Wa[i];
    }
    if (tid < 256) { sBh[tid] = bh[tid]; sH[tid] = 0.f; }
    if (tid < 32)  sBk[tid] = bk[tid];
    if (tid < 512) sXm[tid] = xmean[b*512 + tid];
    float wb  = (tid < 256) ? Wbeta[tid] : 0.f;
    float wgr = (tid < 256) ? Wg[tid] : 0.f;
    float bb  = bbeta[0];

    // Wh f16x2 register cache: row i = tid>>1, half q = tid&1
    unsigned int wh[80];
    {
        const int i = tid >> 1, q = tid & 1;
        const float* wp = Wh + i*320 + q*160;
        #pragma unroll
        for (int jj = 0; jj < 80; ++jj) {
            float2 v = *(const float2*)&wp[2*jj];
            __half2 h2 = __floats2half2_rn(v.x, v.y);
            wh[jj] = *(unsigned int*)&h2;
        }
    }

    const int n0 = 2*tid;
    float c0[32], c1[32];

    // ---- init: c = layernorm(x0) over (N,M); publish stats for replay
    {
        const float* x0 = xfeat + (size_t)(b*16)*32768;
        float sum = 0.f, ss = 0.f;
        #pragma unroll
        for (int m = 0; m < 32; ++m) {
            float2 v = *(const float2*)&x0[m*1024 + n0];
            c0[m] = v.x; c1[m] = v.y;
            sum += v.x + v.y; ss += v.x*v.x + v.y*v.y;
        }
        #pragma unroll
        for (int d = 32; d > 0; d >>= 1) { sum += __shfl_xor(sum, d, 64); ss += __shfl_xor(ss, d, 64); }
        if (lane == 0) { sRedL[wid] = sum; sRedL[8+wid] = ss; }
        __syncthreads();
        float S = 0.f, SS = 0.f;
        #pragma unroll
        for (int i = 0; i < 8; ++i) { S += sRedL[i]; SS += sRedL[8+i]; }
        float mu = S * (1.f/32768.f);
        float var = SS * (1.f/32768.f) - mu*mu;
        float rs = rsqrtf(var + 1e-5f);
        if (tid == 0) { lnst[b*2] = mu; lnst[b*2+1] = rs; }
        #pragma unroll
        for (int m = 0; m < 32; ++m) { c0[m] = (c0[m]-mu)*rs; c1[m] = (c1[m]-mu)*rs; }
    }

    // prefetch x_0 (f16, transposed rows n0,n0+1 -> 128 contiguous bytes)
    uint4 xb[8];
    {
        const uint4* xrow = (const uint4*)(xh + (size_t)(b*16)*32768) + 8*tid;
        #pragma unroll
        for (int i = 0; i < 8; ++i) xb[i] = xrow[i];
    }
    __syncthreads();

    float ex0 = 0.f, ex1 = 0.f, w0 = 0.f, w1 = 0.f;
    const int rm = ((lane&1)<<4)|((lane&2)<<2)|(lane&4)|((lane&8)>>2)|((lane&16)>>4); // rev5(lane&31)

    for (int t = 0; t < 16; ++t) {
        // ---- A: k = tanh(Wk h + bk); beta partials; stage inp = [h, ., xmean]
        {
            const int m = tid >> 4, j = tid & 15;
            float s = 0.f;
            #pragma unroll
            for (int jj = 0; jj < 16; ++jj) s += sWk[m*256 + j + 16*jj] * sH[j + 16*jj];
            s += __shfl_down(s, 8, 16); s += __shfl_down(s, 4, 16);
            s += __shfl_down(s, 2, 16); s += __shfl_down(s, 1, 16);
            if (j == 0) sK[m] = tanhf(s + sBk[m]);
            float p = (tid < 256) ? wb * sH[tid] : 0.f;
            #pragma unroll
            for (int d = 32; d > 0; d >>= 1) p += __shfl_xor(p, d, 64);
            if (lane == 0 && wid < 4) sRedB[wid] = p;
            if (tid < 256) sInp[tid] = sH[tid];
            if (tid < 32)  sInp[288 + tid] = sXm[t*32 + tid];
        }
        __syncthreads();

        // ---- B: cosine sims, exp weights, denom partials, r partials (vector butterfly)
        {
            float x = sRedB[0] + sRedB[1] + sRedB[2] + sRedB[3] + bb;
            float beta = (x > 20.f) ? x : log1pf(expf(x));
            float dot0 = 0.f, dot1 = 0.f, cn20 = 0.f, cn21 = 0.f, kn2 = 0.f;
            #pragma unroll
            for (int q = 0; q < 8; ++q) {
                float4 k4 = *(const float4*)&sK[4*q];
                dot0 += c0[4*q]*k4.x + c0[4*q+1]*k4.y + c0[4*q+2]*k4.z + c0[4*q+3]*k4.w;
                dot1 += c1[4*q]*k4.x + c1[4*q+1]*k4.y + c1[4*q+2]*k4.z + c1[4*q+3]*k4.w;
                cn20 += c0[4*q]*c0[4*q] + c0[4*q+1]*c0[4*q+1] + c0[4*q+2]*c0[4*q+2] + c0[4*q+3]*c0[4*q+3];
                cn21 += c1[4*q]*c1[4*q] + c1[4*q+1]*c1[4*q+1] + c1[4*q+2]*c1[4*q+2] + c1[4*q+3]*c1[4*q+3];
                kn2  += k4.x*k4.x + k4.y*k4.y + k4.z*k4.z + k4.w*k4.w;
            }
            float kinv = 1.f / (sqrtf(kn2) + 1e-8f);
            float s0 = dot0 * kinv / (sqrtf(cn20) + 1e-8f);
            float s1 = dot1 * kinv / (sqrtf(cn21) + 1e-8f);
            ex0 = expf(beta * s0);
            ex1 = expf(beta * s1);
            float es = ex0 + ex1;
            #pragma unroll
            for (int d = 32; d > 0; d >>= 1) es += __shfl_xor(es, d, 64);
            if (lane == 0) sRedD[wid] = es;
            // vector butterfly: reduce v[32] across the wave, one component per lane
            float v[32];
            #pragma unroll
            for (int m = 0; m < 32; ++m) v[m] = ex0*c0[m] + ex1*c1[m];
            #pragma unroll
            for (int i = 0; i < 16; ++i) { float sd = (lane&1)? v[i] : v[i+16]; float rc = __shfl_xor(sd, 1, 64); v[i] = ((lane&1)? v[i+16] : v[i]) + rc; }
            #pragma unroll
            for (int i = 0; i < 8; ++i)  { float sd = (lane&2)? v[i] : v[i+8];  float rc = __shfl_xor(sd, 2, 64); v[i] = ((lane&2)? v[i+8]  : v[i]) + rc; }
            #pragma unroll
            for (int i = 0; i < 4; ++i)  { float sd = (lane&4)? v[i] : v[i+4];  float rc = __shfl_xor(sd, 4, 64); v[i] = ((lane&4)? v[i+4]  : v[i]) + rc; }
            #pragma unroll
            for (int i = 0; i < 2; ++i)  { float sd = (lane&8)? v[i] : v[i+2];  float rc = __shfl_xor(sd, 8, 64); v[i] = ((lane&8)? v[i+2]  : v[i]) + rc; }
            { float sd = (lane&16)? v[0] : v[1]; float rc = __shfl_xor(sd, 16, 64); v[0] = ((lane&16)? v[1] : v[0]) + rc; }
            v[0] += __shfl_xor(v[0], 32, 64);
            if (lane < 32) sRedC[wid*32 + rm] = v[0];
        }
        __syncthreads();

        // ---- C': combine r partials -> sInp[256+m]
        if (tid < 32) {
            float den = sRedD[0]+sRedD[1]+sRedD[2]+sRedD[3]+sRedD[4]+sRedD[5]+sRedD[6]+sRedD[7];
            float inv = 1.f / den;
            float r = 0.f;
            #pragma unroll
            for (int w = 0; w < 8; ++w) r += sRedC[w*32 + tid];
            sInp[256 + tid] = r * inv;
        }
        __syncthreads();

        // ---- D: h_new = tanh(Wh inp + bh); also store w to global
        {
            const int i = tid >> 1, q = tid & 1;
            const float* ip = &sInp[q*160];
            float s = 0.f;
            #pragma unroll
            for (int jj = 0; jj < 40; ++jj) {
                float4 v = *(const float4*)&ip[4*jj];
                __half2 a2 = *(__half2*)&wh[2*jj];
                __half2 b2 = *(__half2*)&wh[2*jj+1];
                float2 fa = __half22float2(a2), fb = __half22float2(b2);
                s += fa.x*v.x + fa.y*v.y + fb.x*v.z + fb.y*v.w;
            }
            s += __shfl_down(s, 1, 2);
            if (q == 0) sH[i] = tanhf(s + sBh[i]);
            float den = sRedD[0]+sRedD[1]+sRedD[2]+sRedD[3]+sRedD[4]+sRedD[5]+sRedD[6]+sRedD[7];
            float inv = 1.f / den;
            w0 = ex0 * inv; w1 = ex1 * inv;
            *(float2*)&wbuf[(size_t)(b*16 + t)*1024 + n0] = make_float2(w0, w1);
        }
        __syncthreads();

        // ---- E: e = sig(We h), a = tanh(Wa h), g partials; publish e/a to global
        {
            const int m = tid >> 4, j = tid & 15;
            float se = 0.f, sa = 0.f;
            #pragma unroll
            for (int jj = 0; jj < 16; ++jj) {
                float hv = sH[j + 16*jj];
                se += sWe[m*256 + j + 16*jj]*hv;
                sa += sWa[m*256 + j + 16*jj]*hv;
            }
            se += __shfl_down(se, 8, 16); sa += __shfl_down(sa, 8, 16);
            se += __shfl_down(se, 4, 16); sa += __shfl_down(sa, 4, 16);
            se += __shfl_down(se, 2, 16); sa += __shfl_down(sa, 2, 16);
            se += __shfl_down(se, 1, 16); sa += __shfl_down(sa, 1, 16);
            if (j == 0) {
                float e = 1.f/(1.f + expf(-se));
                float a = tanhf(sa);
                sE[m] = e; sA[m] = a;
                eag[(size_t)(b*16 + t)*80 + m]      = e;
                eag[(size_t)(b*16 + t)*80 + 32 + m] = a;
            }
            float p = (tid < 256) ? wgr * sH[tid] : 0.f;
            #pragma unroll
            for (int d = 32; d > 0; d >>= 1) p += __shfl_xor(p, d, 64);
            if (lane == 0 && wid < 4) sRedG[wid] = p;
        }
        __syncthreads();

        // ---- F: c update in registers (f16 x); prefetch next x
        {
            float gx = sRedG[0] + sRedG[1] + sRedG[2] + sRedG[3];
            float gg = 1.f / (1.f + expf(-gx));
            float omg = 1.f - gg;
            if (tid == 0) eag[(size_t)(b*16 + t)*80 + 64] = gg;
            const __half* xp = (const __half*)xb;
            #pragma unroll
            for (int m = 0; m < 32; ++m) {
                float e = sE[m], a = sA[m];
                float x0v = __half2float(xp[m]);
                float x1v = __half2float(xp[32 + m]);
                c0[m] = omg*(c0[m]*(1.f - w0*e) + w0*a) + gg*x0v;
                c1[m] = omg*(c1[m]*(1.f - w1*e) + w1*a) + gg*x1v;
            }
            if (t < 15) {
                const uint4* xrow = (const uint4*)(xh + (size_t)(b*16 + t + 1)*32768) + 8*tid;
                #pragma unroll
                for (int i = 0; i < 8; ++i) xb[i] = xrow[i];
            }
        }
        __syncthreads();
    }
}

// ---------------- replay: reconstruct cseq from scalars, fully parallel
__global__ __launch_bounds__(256) void ntm_replay_kernel(
    const float* __restrict__ xfeat, const float* __restrict__ wbuf,
    const float* __restrict__ eag, const float* __restrict__ lnst,
    float* __restrict__ cseq)
{
    const int slab = blockIdx.x;    // 16 slabs of 64 n
    const int b    = blockIdx.y;    // 8
    const int tid  = threadIdx.x;
    const int m    = tid >> 3;      // 32
    const int ns   = tid & 7;       // 8 subgroups of 8 n
    const int n0   = slab*64 + ns*8;
    const float mu = lnst[b*2], rs = lnst[b*2+1];

    float c[8];
    {
        const float* x0 = xfeat + (size_t)(b*16)*32768 + m*1024 + n0;
        float4 a = *(const float4*)x0;
        float4 bv = *(const float4*)(x0 + 4);
        c[0]=(a.x-mu)*rs; c[1]=(a.y-mu)*rs; c[2]=(a.z-mu)*rs; c[3]=(a.w-mu)*rs;
        c[4]=(bv.x-mu)*rs; c[5]=(bv.y-mu)*rs; c[6]=(bv.z-mu)*rs; c[7]=(bv.w-mu)*rs;
    }
    for (int t = 0; t < 16; ++t) {
        const size_t bt = (size_t)(b*16 + t);
        const float* wp = &wbuf[bt*1024 + n0];
        float4 wA = *(const float4*)wp;
        float4 wB = *(const float4*)(wp + 4);
        float e = eag[bt*80 + m];
        float a = eag[bt*80 + 32 + m];
        float g = eag[bt*80 + 64];
        float omg = 1.f - g;
        const float* xp = &xfeat[bt*32768 + m*1024 + n0];
        float4 xA = *(const float4*)xp;
        float4 xB = *(const float4*)(xp + 4);
        c[0] = omg*(c[0]*(1.f - wA.x*e) + wA.x*a) + g*xA.x;
        c[1] = omg*(c[1]*(1.f - wA.y*e) + wA.y*a) + g*xA.y;
        c[2] = omg*(c[2]*(1.f - wA.z*e) + wA.z*a) + g*xA.z;
        c[3] = omg*(c[3]*(1.f - wA.w*e) + wA.w*a) + g*xA.w;
        c[4] = omg*(c[4]*(1.f - wB.x*e) + wB.x*a) + g*xB.x;
        c[5] = omg*(c[5]*(1.f - wB.y*e) + wB.y*a) + g*xB.y;
        c[6] = omg*(c[6]*(1.f - wB.z*e) + wB.z*a) + g*xB.z;
        c[7] = omg*(c[7]*(1.f - wB.w*e) + wB.w*a) + g*xB.w;
        float* op = &cseq[bt*32768 + m*1024 + n0];
        *(float4*)op       = make_float4(c[0], c[1], c[2], c[3]);
        *(float4*)(op + 4) = make_float4(c[4], c[5], c[6], c[7]);
    }
}

// ---------------- rfft2 of 32x32 windowed tile via 2-stage DFT; one block per (bt,m) image
__global__ __launch_bounds__(256) void fft_fwd_kernel(const float* __restrict__ src,
                                                      const float* __restrict__ cosw,
                                                      float* __restrict__ dst)
{
    const int img = blockIdx.x;
    const int tid = threadIdx.x;
    __shared__ float sY[1024];
    __shared__ float sR[32*17*2];
    __shared__ float ct[32], st[32];
    if (tid < 32) {
        float sv, cv;
        sincosf(TWOPI_32 * (float)tid, &sv, &cv);
        ct[tid] = cv; st[tid] = sv;
    }
    {
        float4 v = *(const float4*)&src[(size_t)img*1024 + tid*4];
        float4 c = *(const float4*)&cosw[tid*4];
        float4 o; o.x = v.x*c.x; o.y = v.y*c.y; o.z = v.z*c.z; o.w = v.w*c.w;
        *(float4*)&sY[tid*4] = o;
    }
    __syncthreads();
    // stage 1: rfft along w: R[h][k] = sum_w y e^{-2pi i w k/32}
    for (int idx = tid; idx < 544; idx += 256) {
        int h = idx / 17;
        int k = idx - h*17;
        const float* y = &sY[h*32];
        float re = 0.f, im = 0.f;
        #pragma unroll
        for (int wq = 0; wq < 32; ++wq) {
            int a = (wq*k) & 31;
            re += y[wq] * ct[a];
            im -= y[wq] * st[a];
        }
        sR[idx*2] = re; sR[idx*2+1] = im;
    }
    __syncthreads();
    // stage 2: full fft along h
    for (int idx = tid; idx < 544; idx += 256) {
        int j = idx / 17;
        int k = idx - j*17;
        float re = 0.f, im = 0.f;
        #pragma unroll
        for (int h = 0; h < 32; ++h) {
            float ar = sR[(h*17+k)*2], ai = sR[(h*17+k)*2+1];
            int a = (h*j) & 31;
            float c = ct[a], s = st[a];
            re += ar*c + ai*s;
            im += ai*c - ar*s;
        }
        dst[((size_t)img*544 + idx)*2]     = re;
        dst[((size_t)img*544 + idx)*2 + 1] = im;
    }
}

// ---------------- channel-sum DCF combine (parallel: 1 thread per (bt,idx))
__global__ __launch_bounds__(256) void combine_kernel(const float* __restrict__ cfft,
                                                      const float* __restrict__ zfft,
                                                      const float* __restrict__ yf,
                                                      float* __restrict__ rfreq)
{
    int gid = blockIdx.x*256 + threadIdx.x;
    if (gid >= 128*544) return;
    int bt  = gid / 544;
    int idx = gid - bt*544;
    float kzz = 0.f, kxr = 0.f, kxi = 0.f;
    #pragma unroll 4
    for (int m = 0; m < 32; ++m) {
        size_t base = ((size_t)(bt*32 + m)*544 + idx)*2;
        float2 c = *(const float2*)&cfft[base];
        float2 z = *(const float2*)&zfft[base];
        kzz += c.x*c.x + c.y*c.y;
        kxr += z.x*c.x + z.y*c.y;   // z * conj(c)
        kxi += z.y*c.x - z.x*c.y;
    }
    float den = 1.f / (kzz + 1e-4f);
    float2 y = *(const float2*)&yf[idx*2];
    float ar = y.x*den, ai = y.y*den;
    *(float2*)&rfreq[(size_t)gid*2] = make_float2(kxr*ar - kxi*ai, kxr*ai + kxi*ar);
}

// ---------------- irfft2 back to 32x32 real response; one block per bt
__global__ __launch_bounds__(256) void ifft_kernel(const float* __restrict__ rfreq,
                                                   float* __restrict__ out)
{
    const int bt  = blockIdx.x;
    const int tid = threadIdx.x;
    __shared__ float sG[544*2];
    __shared__ float sS[544*2];
    __shared__ float ct[32], st[32];
    if (tid < 32) {
        float sv, cv;
        sincosf(TWOPI_32 * (float)tid, &sv, &cv);
        ct[tid] = cv; st[tid] = sv;
    }
    for (int i = tid; i < 1088; i += 256) sG[i] = rfreq[(size_t)bt*1088 + i];
    __syncthreads();
    // stage 1: inverse fft along j
    for (int idx = tid; idx < 544; idx += 256) {
        int h = idx / 17;
        int k = idx - h*17;
        float re = 0.f, im = 0.f;
        #pragma unroll
        for (int j = 0; j < 32; ++j) {
            float gr = sG[(j*17+k)*2], gi = sG[(j*17+k)*2+1];
            int a = (h*j) & 31;
            float c = ct[a], s = st[a];
            re += gr*c - gi*s;
            im += gr*s + gi*c;
        }
        sS[(h*17+k)*2] = re; sS[(h*17+k)*2+1] = im;
    }
    __syncthreads();
    // stage 2: inverse rfft along w with hermitian extension; scale 1/1024
    #pragma unroll
    for (int p = 0; p < 4; ++p) {
        int pos = p*256 + tid;
        int h = pos >> 5, wq = pos & 31;
        float acc = sS[(h*17)*2];
        #pragma unroll
        for (int k = 1; k < 16; ++k) {
            int a = (wq*k) & 31;
            acc += 2.f*(sS[(h*17+k)*2]*ct[a] - sS[(h*17+k)*2+1]*st[a]);
        }
        acc += sS[(h*17+16)*2] * ((wq & 1) ? -1.f : 1.f);
        out[(size_t)bt*1024 + pos] = acc * (1.f/1024.f);
    }
}

extern "C" void kernel_launch(void* const* d_in, const int* in_sizes, int n_in,
                              void* d_out, int out_size, void* d_ws, size_t ws_size,
                              hipStream_t stream)
{
    const float* x_i   = (const float*)d_in[0];
    const float* z_i   = (const float*)d_in[1];
    const float* c1w   = (const float*)d_in[2];
    const float* c1b   = (const float*)d_in[3];
    const float* c2w   = (const float*)d_in[4];
    const float* c2b   = (const float*)d_in[5];
    const float* Wk    = (const float*)d_in[6];
    const float* bk    = (const float*)d_in[7];
    const float* Wbeta = (const float*)d_in[8];
    const float* bbeta = (const float*)d_in[9];
    const float* Wh    = (const float*)d_in[10];
    const float* bh    = (const float*)d_in[11];
    const float* We    = (const float*)d_in[12];
    const float* Wa    = (const float*)d_in[13];
    const float* Wg    = (const float*)d_in[14];
    const float* cosw  = (const float*)d_in[15];
    const float* yf    = (const float*)d_in[16];
    float* out = (float*)d_out;
    float* ws  = (float*)d_ws;

    // workspace layout (floats); peak ~118 MB (unchanged footprint)
    float*  buf1  = ws;                 // conv1 out / later fft+ntm scratch region, 16,777,216 f
    float*  xfeat = ws + 16777216;      // 4,194,304
    float*  zfeat = ws + 20971520;      // 4,194,304
    float*  cseq  = ws + 25165824;      // 4,194,304
    float*  rfreq = ws + 29360128;      // 139,264
    float*  xmb   = ws + 29499392;      // 4,096
    // region inside buf1, used after conv stage completes:
    float*  cfft  = buf1;               // 4,456,448 f
    float*  zfft  = buf1 + 4456448;     // 4,456,448 f (ends 8,912,896)
    __half* xhb   = (__half*)(ws + 9000000);   // 4,194,304 halfs (2,097,152 f)
    float*  wbuf  = ws + 11100000;      // 131,072 f
    float*  eag   = ws + 11240000;      // 10,240 f
    float*  lnstp = ws + 11251000;      // 16 f

    dim3 b256(256);
    conv1_kernel<<<dim3(4,128), b256, 0, stream>>>(x_i, c1w, c1b, buf1);
    conv2_kernel<<<dim3(8,128), b256, 0, stream>>>(buf1, c2w, c2b, xfeat);
    conv1_kernel<<<dim3(4,128), b256, 0, stream>>>(z_i, c1w, c1b, buf1);
    conv2_kernel<<<dim3(8,128), b256, 0, stream>>>(buf1, c2w, c2b, zfeat);
    xhalf_kernel<<<128, b256, 0, stream>>>(xfeat, xhb);
    xmean_kernel<<<1024, b256, 0, stream>>>(xfeat, xmb);
    ntm_scal_kernel<<<8, 512, 0, stream>>>(xfeat, xhb, xmb, Wk, bk, Wbeta, bbeta,
                                           Wh, bh, We, Wa, Wg, wbuf, eag, lnstp);
    ntm_replay_kernel<<<dim3(16,8), b256, 0, stream>>>(xfeat, wbuf, eag, lnstp, cseq);
    fft_fwd_kernel<<<4096, b256, 0, stream>>>(cseq, cosw, cfft);
    fft_fwd_kernel<<<4096, b256, 0, stream>>>(zfeat, cosw, zfft);
    combine_kernel<<<272, b256, 0, stream>>>(cfft, zfft, yf, rfreq);
    ifft_kernel<<<128, b256, 0, stream>>>(rfreq, out);
}

// Round 4
// 861.487 us; speedup vs baseline: 1.1519x; 1.1519x over previous
//
#include <hip/hip_runtime.h>
#include <hip/hip_fp16.h>
#include <math.h>

// Problem constants
// B=8, T=16, IMG=128, CF=32, WO=HO=32, N=1024, M=32, DH=256
// conv SAME stride2: pad_lo=0, pad_hi=1  ->  in_idx = 2*out + k

#define TWOPI_32 0.19634954084936207f  // 2*pi/32

// ---------------- conv1: [img][3][128][128] -> [img][32][64][64], stride2 SAME, ReLU
__global__ __launch_bounds__(256) void conv1_kernel(const float* __restrict__ in,
                                                    const float* __restrict__ w,
                                                    const float* __restrict__ bias,
                                                    float* __restrict__ out)
{
    const int strip = blockIdx.x;   // 4 strips of 16 output rows
    const int img   = blockIdx.y;   // 128 images
    const int tid   = threadIdx.x;
    __shared__ float sIn[3*33*130];
    const int iy0 = strip * 32;
    for (int idx = tid; idx < 3*33*130; idx += 256) {
        int ic  = idx / (33*130);
        int rem = idx - ic*(33*130);
        int li  = rem / 130;
        int col = rem - li*130;
        int iy  = iy0 + li;
        float v = 0.f;
        if (iy < 128 && col < 128)
            v = in[(((size_t)img*3 + ic)*128 + iy)*128 + col];
        sIn[idx] = v;
    }
    __syncthreads();
    const int oy0 = strip*16;
    #pragma unroll
    for (int p = 0; p < 4; ++p) {
        int pos = p*256 + tid;       // 1024 positions: 16 rows x 64 cols
        int ly = pos >> 6;
        int ox = pos & 63;
        float r[27];
        #pragma unroll
        for (int ic = 0; ic < 3; ++ic)
            #pragma unroll
            for (int dy = 0; dy < 3; ++dy)
                #pragma unroll
                for (int dx = 0; dx < 3; ++dx)
                    r[(ic*3+dy)*3+dx] = sIn[ic*(33*130) + (2*ly+dy)*130 + 2*ox + dx];
        for (int oc = 0; oc < 32; ++oc) {
            float acc = bias[oc];
            #pragma unroll
            for (int q = 0; q < 27; ++q)
                acc += r[q] * w[oc*27 + q];
            out[(((size_t)img*32 + oc)*64 + (oy0+ly))*64 + ox] = fmaxf(acc, 0.f);
        }
    }
}

// ---------------- conv2: [img][32][64][64] -> [img][32][32][32], stride2 SAME, ReLU
__global__ __launch_bounds__(256) void conv2_kernel(const float* __restrict__ in,
                                                    const float* __restrict__ w,
                                                    const float* __restrict__ bias,
                                                    float* __restrict__ out)
{
    const int strip = blockIdx.x;   // 8 strips of 4 output rows
    const int img   = blockIdx.y;
    const int tid   = threadIdx.x;
    __shared__ float sIn[32*9*66];
    const int iy0 = strip*8;
    for (int idx = tid; idx < 32*9*66; idx += 256) {
        int ic  = idx / (9*66);
        int rem = idx - ic*(9*66);
        int li  = rem / 66;
        int col = rem - li*66;
        int iy  = iy0 + li;
        float v = 0.f;
        if (iy < 64 && col < 64)
            v = in[(((size_t)img*32 + ic)*64 + iy)*64 + col];
        sIn[idx] = v;
    }
    __syncthreads();
    const int posl = tid & 127;     // 128 positions: 4 rows x 32 cols
    const int half = tid >> 7;      // 2 halves of 16 out-channels
    const int ly = posl >> 5;
    const int ox = posl & 31;
    float acc[16];
    #pragma unroll
    for (int j = 0; j < 16; ++j) acc[j] = 0.f;
    for (int ic = 0; ic < 32; ++ic) {
        float r[9];
        #pragma unroll
        for (int dy = 0; dy < 3; ++dy)
            #pragma unroll
            for (int dx = 0; dx < 3; ++dx)
                r[dy*3+dx] = sIn[ic*(9*66) + (2*ly+dy)*66 + 2*ox + dx];
        #pragma unroll
        for (int j = 0; j < 16; ++j) {
            int oc = half*16 + j;
            const float* wp = &w[(oc*32 + ic)*9];
            float a = acc[j];
            #pragma unroll
            for (int q = 0; q < 9; ++q) a += r[q]*wp[q];
            acc[j] = a;
        }
    }
    const int oy = strip*4 + ly;
    #pragma unroll
    for (int j = 0; j < 16; ++j) {
        int oc = half*16 + j;
        out[(((size_t)img*32 + oc)*32 + oy)*32 + ox] = fmaxf(acc[j] + bias[oc], 0.f);
    }
}

// ---------------- pack: f16 weight layouts for the serial kernel
// whhP [32 chunks][256 rows][8 halves]  <- Wh cols 0..255  (chunk c=q*16+k covers cols q*128+k*8..+8)
// whrxP[256][64]                        <- Wh cols 256..319
// wkP/weP/waP [(m*16+j)*16+jj]          <- W[m][j+16*jj]
__global__ __launch_bounds__(256) void pack_kernel(const float* __restrict__ Wh,
    const float* __restrict__ Wk, const float* __restrict__ We, const float* __restrict__ Wa,
    __half* __restrict__ whhP, __half* __restrict__ whrxP,
    __half* __restrict__ wkP, __half* __restrict__ weP, __half* __restrict__ waP)
{
    int idx = blockIdx.x*256 + threadIdx.x;
    if (idx < 65536) {
        int e = idx & 7, i = (idx >> 3) & 255, c = idx >> 11;
        int q = c >> 4, k = c & 15;
        whhP[idx] = __float2half(Wh[i*320 + q*128 + k*8 + e]);
    }
    if (idx < 16384) {
        int i = idx >> 6, s2 = idx & 63;
        whrxP[idx] = __float2half(Wh[i*320 + 256 + s2]);
    }
    if (idx < 8192) {
        int m = idx >> 8, j = (idx >> 4) & 15, jj = idx & 15;
        wkP[idx] = __float2half(Wk[m*256 + j + 16*jj]);
        weP[idx] = __float2half(We[m*256 + j + 16*jj]);
        waP[idx] = __float2half(Wa[m*256 + j + 16*jj]);
    }
}

// ---------------- xhalf: transpose xfeat [bt][m][n] f32 -> xh [bt][n][m] f16
__global__ __launch_bounds__(256) void xhalf_kernel(const float* __restrict__ xf,
                                                    __half* __restrict__ xh)
{
    const int bt  = blockIdx.x;
    const int tid = threadIdx.x;
    __shared__ float sT[32][257];
    const float* src = xf + (size_t)bt*32768;
    __half* dst = xh + (size_t)bt*32768;
    for (int tt = 0; tt < 4; ++tt) {
        #pragma unroll
        for (int m = 0; m < 32; ++m)
            sT[m][tid] = src[m*1024 + tt*256 + tid];
        __syncthreads();
        uint4 o[4];
        unsigned int* ou = (unsigned int*)o;
        #pragma unroll
        for (int k = 0; k < 16; ++k) {
            __half2 h2 = __floats2half2_rn(sT[2*k][tid], sT[2*k+1][tid]);
            ou[k] = *(unsigned int*)&h2;
        }
        uint4* dp = (uint4*)(dst + (size_t)(tt*256 + tid)*32);
        dp[0] = o[0]; dp[1] = o[1]; dp[2] = o[2]; dp[3] = o[3];
        __syncthreads();
    }
}

// ---------------- xmean: mean over n of xfeat rows [(bt*32+m)][1024]
__global__ __launch_bounds__(256) void xmean_kernel(const float* __restrict__ xfeat,
                                                    float* __restrict__ xmean)
{
    const int row  = blockIdx.x*4 + (threadIdx.x >> 6);   // 4096 rows
    const int lane = threadIdx.x & 63;
    const float* p = xfeat + (size_t)row*1024;
    float s = 0.f;
    #pragma unroll
    for (int jj = 0; jj < 16; ++jj) s += p[lane + 64*jj];
    #pragma unroll
    for (int d = 32; d > 0; d >>= 1) s += __shfl_xor(s, d, 64);
    if (lane == 0) xmean[row] = s * (1.f/1024.f);
}

// ---------------- NTM scalar recurrence: one block per batch, 512 threads.
// Spill-proof design: only c0/c1[32] persistent in VGPRs (~80 regs demand).
// Wh h-part f16 in LDS (128 KB); Wh rx-part, Wk, We, Wa streamed f16 from L2.
// Emits only: w_t[n] (wbuf), e/a/g (eag), layernorm stats (lnst).
__global__ __launch_bounds__(512, 2) void ntm_scal_kernel(
    const float* __restrict__ xfeat, const __half* __restrict__ xh,
    const float* __restrict__ xmean,
    const __half* __restrict__ whhP, const __half* __restrict__ whrxP,
    const __half* __restrict__ wkP, const __half* __restrict__ weP,
    const __half* __restrict__ waP,
    const float* __restrict__ bk, const float* __restrict__ Wbeta,
    const float* __restrict__ bbeta, const float* __restrict__ bh,
    const float* __restrict__ Wg,
    float* __restrict__ wbuf, float* __restrict__ eag, float* __restrict__ lnst)
{
    const int b    = blockIdx.x;
    const int tid  = threadIdx.x;
    const int lane = tid & 63;
    const int wid  = tid >> 6;

    __shared__ __align__(16) __half sWhh[65536];   // 128 KB
    __shared__ __align__(16) float sHbuf[2][256];
    __shared__ __align__(16) float sK[32];
    __shared__ __align__(16) float sXm[512];
    __shared__ float sRedC[256];
    __shared__ float sRedD[8];
    __shared__ float sRedL[16];
    __shared__ __align__(16) float sR32[32];
    __shared__ __align__(16) float sE[32];
    __shared__ __align__(16) float sA[32];
    __shared__ float sBk[32];
    __shared__ float sBh[256];

    // stage Wh h-part into LDS (one-time, 131072 B)
    {
        const uint4* src = (const uint4*)whhP;
        uint4* dst = (uint4*)sWhh;
        for (int i2 = tid; i2 < 8192; i2 += 512) dst[i2] = src[i2];
    }
    if (tid < 256) { sBh[tid] = bh[tid]; sHbuf[0][tid] = 0.f; }
    if (tid < 32)  sBk[tid] = bk[tid];
    if (tid < 512) sXm[tid] = xmean[b*512 + tid];
    float4 wbeta4 = *(const float4*)&Wbeta[(size_t)lane*4];
    float4 wg4    = *(const float4*)&Wg[(size_t)lane*4];
    float bb = bbeta[0];

    const int n0 = 2*tid;
    float c0[32], c1[32];

    // ---- init: c = layernorm(x0) over (N,M); publish stats for replay
    {
        const float* x0 = xfeat + (size_t)(b*16)*32768;
        float sum = 0.f, ss = 0.f;
        #pragma unroll
        for (int m = 0; m < 32; ++m) {
            float2 v = *(const float2*)&x0[m*1024 + n0];
            c0[m] = v.x; c1[m] = v.y;
            sum += v.x + v.y; ss += v.x*v.x + v.y*v.y;
        }
        #pragma unroll
        for (int d = 32; d > 0; d >>= 1) { sum += __shfl_xor(sum, d, 64); ss += __shfl_xor(ss, d, 64); }
        if (lane == 0) { sRedL[wid] = sum; sRedL[8+wid] = ss; }
        __syncthreads();
        float S = 0.f, SS = 0.f;
        #pragma unroll
        for (int i = 0; i < 8; ++i) { S += sRedL[i]; SS += sRedL[8+i]; }
        float mu = S * (1.f/32768.f);
        float var = SS * (1.f/32768.f) - mu*mu;
        float rs = rsqrtf(var + 1e-5f);
        if (tid == 0) { lnst[b*2] = mu; lnst[b*2+1] = rs; }
        #pragma unroll
        for (int m = 0; m < 32; ++m) { c0[m] = (c0[m]-mu)*rs; c1[m] = (c1[m]-mu)*rs; }
    }
    __syncthreads();   // covers sWhh staging, sHbuf[0] zeros, sXm, sBk, sBh

    float ex0 = 0.f, ex1 = 0.f, w0 = 0.f, w1 = 0.f;
    const int rm = ((lane&1)<<4)|((lane&2)<<2)|(lane&4)|((lane&8)>>2)|((lane&16)>>4); // rev5(lane&31)

    #pragma unroll 1
    for (int t = 0; t < 16; ++t) {
        const int cur = t & 1, nxt = cur ^ 1;
        const float* hold = &sHbuf[cur][0];
        float betav;

        // ---- P1: k = tanh(Wk h + bk) (distributed, f16 weights streamed); beta per-wave redundant
        {
            const int m = tid >> 4, j = tid & 15;
            const uint4* wkp = (const uint4*)(wkP + (size_t)(m*16 + j)*16);
            uint4 wk0 = wkp[0], wk1 = wkp[1];
            float s = 0.f;
            const __half2* a2 = (const __half2*)&wk0;
            const __half2* b2 = (const __half2*)&wk1;
            #pragma unroll
            for (int d = 0; d < 4; ++d) {
                float2 p = __half22float2(a2[d]);
                s += p.x * hold[j + 16*(2*d)] + p.y * hold[j + 16*(2*d+1)];
            }
            #pragma unroll
            for (int d = 0; d < 4; ++d) {
                float2 p = __half22float2(b2[d]);
                s += p.x * hold[j + 16*(8+2*d)] + p.y * hold[j + 16*(8+2*d+1)];
            }
            s += __shfl_down(s, 8, 16); s += __shfl_down(s, 4, 16);
            s += __shfl_down(s, 2, 16); s += __shfl_down(s, 1, 16);
            if (j == 0) sK[m] = tanhf(s + sBk[m]);
            // beta (redundant per wave)
            float4 h4 = *(const float4*)&hold[lane*4];
            float p = wbeta4.x*h4.x + wbeta4.y*h4.y + wbeta4.z*h4.z + wbeta4.w*h4.w;
            #pragma unroll
            for (int d = 32; d > 0; d >>= 1) p += __shfl_xor(p, d, 64);
            float x = p + bb;
            betav = (x > 20.f) ? x : log1pf(expf(x));
        }
        __syncthreads();   // bar1: sK ready

        // ---- P2: cosine sims, exp weights, denom partials, r partials (vector butterfly)
        {
            float beta = betav;
            float dot0 = 0.f, dot1 = 0.f, cn20 = 0.f, cn21 = 0.f, kn2 = 0.f;
            #pragma unroll
            for (int q = 0; q < 8; ++q) {
                float4 k4 = *(const float4*)&sK[4*q];
                dot0 += c0[4*q]*k4.x + c0[4*q+1]*k4.y + c0[4*q+2]*k4.z + c0[4*q+3]*k4.w;
                dot1 += c1[4*q]*k4.x + c1[4*q+1]*k4.y + c1[4*q+2]*k4.z + c1[4*q+3]*k4.w;
                cn20 += c0[4*q]*c0[4*q] + c0[4*q+1]*c0[4*q+1] + c0[4*q+2]*c0[4*q+2] + c0[4*q+3]*c0[4*q+3];
                cn21 += c1[4*q]*c1[4*q] + c1[4*q+1]*c1[4*q+1] + c1[4*q+2]*c1[4*q+2] + c1[4*q+3]*c1[4*q+3];
                kn2  += k4.x*k4.x + k4.y*k4.y + k4.z*k4.z + k4.w*k4.w;
            }
            float kinv = 1.f / (sqrtf(kn2) + 1e-8f);
            float s0 = dot0 * kinv / (sqrtf(cn20) + 1e-8f);
            float s1 = dot1 * kinv / (sqrtf(cn21) + 1e-8f);
            ex0 = expf(beta * s0);
            ex1 = expf(beta * s1);
            float es = ex0 + ex1;
            #pragma unroll
            for (int d = 32; d > 0; d >>= 1) es += __shfl_xor(es, d, 64);
            if (lane == 0) sRedD[wid] = es;
            // vector butterfly: reduce v[32] across the wave, one component per lane
            float v[32];
            #pragma unroll
            for (int m = 0; m < 32; ++m) v[m] = ex0*c0[m] + ex1*c1[m];
            #pragma unroll
            for (int i = 0; i < 16; ++i) { float sd = (lane&1)? v[i] : v[i+16]; float rc = __shfl_xor(sd, 1, 64); v[i] = ((lane&1)? v[i+16] : v[i]) + rc; }
            #pragma unroll
            for (int i = 0; i < 8; ++i)  { float sd = (lane&2)? v[i] : v[i+8];  float rc = __shfl_xor(sd, 2, 64); v[i] = ((lane&2)? v[i+8]  : v[i]) + rc; }
            #pragma unroll
            for (int i = 0; i < 4; ++i)  { float sd = (lane&4)? v[i] : v[i+4];  float rc = __shfl_xor(sd, 4, 64); v[i] = ((lane&4)? v[i+4]  : v[i]) + rc; }
            #pragma unroll
            for (int i = 0; i < 2; ++i)  { float sd = (lane&8)? v[i] : v[i+2];  float rc = __shfl_xor(sd, 8, 64); v[i] = ((lane&8)? v[i+2]  : v[i]) + rc; }
            { float sd = (lane&16)? v[0] : v[1]; float rc = __shfl_xor(sd, 16, 64); v[0] = ((lane&16)? v[1] : v[0]) + rc; }
            v[0] += __shfl_xor(v[0], 32, 64);
            if (lane < 32) sRedC[wid*32 + rm] = v[0];
        }
        __syncthreads();   // bar2: sRedC/sRedD ready

        // ---- P3: r-combine (per-wave redundant), wbuf write, D-dot -> h_new
        {
            float den = sRedD[0]+sRedD[1]+sRedD[2]+sRedD[3]+sRedD[4]+sRedD[5]+sRedD[6]+sRedD[7];
            float inv = 1.f / den;
            w0 = ex0 * inv; w1 = ex1 * inv;
            *(float2*)&wbuf[(size_t)(b*16 + t)*1024 + n0] = make_float2(w0, w1);
            if (lane < 32) {
                float r = 0.f;
                #pragma unroll
                for (int w = 0; w < 8; ++w) r += sRedC[w*32 + lane];
                sR32[lane] = r * inv;
            }
            // D-dot: thread (i = tid>>1, q = tid&1) handles half of row i
            const int i = tid >> 1, q = tid & 1;
            const uint4* wrp = (const uint4*)(whrxP + (size_t)i*64 + q*32);
            uint4 wrx0 = wrp[0], wrx1 = wrp[1], wrx2 = wrp[2], wrx3 = wrp[3];
            float s = 0.f;
            #pragma unroll
            for (int k = 0; k < 16; ++k) {
                uint4 wv = *(const uint4*)&sWhh[(size_t)(((q*16 + k)*256 + i))*8];
                float4 h4a = *(const float4*)&hold[q*128 + k*8];
                float4 h4b = *(const float4*)&hold[q*128 + k*8 + 4];
                const __half2* w2 = (const __half2*)&wv;
                float2 p0 = __half22float2(w2[0]); s += p0.x*h4a.x + p0.y*h4a.y;
                float2 p1 = __half22float2(w2[1]); s += p1.x*h4a.z + p1.y*h4a.w;
                float2 p2 = __half22float2(w2[2]); s += p2.x*h4b.x + p2.y*h4b.y;
                float2 p3 = __half22float2(w2[3]); s += p3.x*h4b.z + p3.y*h4b.w;
            }
            // rx part: q=0 -> r[0..31], q=1 -> xmean[0..31]
            const float* rxsrc = q ? &sXm[t*32] : sR32;
            uint4 wrx[4] = {wrx0, wrx1, wrx2, wrx3};
            #pragma unroll
            for (int c4 = 0; c4 < 4; ++c4) {
                float4 va = *(const float4*)&rxsrc[c4*8];
                float4 vb = *(const float4*)&rxsrc[c4*8 + 4];
                const __half2* w2 = (const __half2*)&wrx[c4];
                float2 p0 = __half22float2(w2[0]); s += p0.x*va.x + p0.y*va.y;
                float2 p1 = __half22float2(w2[1]); s += p1.x*va.z + p1.y*va.w;
                float2 p2 = __half22float2(w2[2]); s += p2.x*vb.x + p2.y*vb.y;
                float2 p3 = __half22float2(w2[3]); s += p3.x*vb.z + p3.y*vb.w;
            }
            s += __shfl_down(s, 1, 2);
            if (q == 0) sHbuf[nxt][i] = tanhf(s + sBh[i]);
        }
        __syncthreads();   // bar3: h_new ready

        // ---- P4a: e = sig(We h), a = tanh(Wa h) (distributed); g per-wave redundant
        float gg;
        {
            const float* hnew = &sHbuf[nxt][0];
            const int m = tid >> 4, j = tid & 15;
            const uint4* wep = (const uint4*)(weP + (size_t)(m*16 + j)*16);
            const uint4* wap = (const uint4*)(waP + (size_t)(m*16 + j)*16);
            uint4 we0 = wep[0], we1 = wep[1];
            uint4 wa0 = wap[0], wa1 = wap[1];
            float se = 0.f, sa = 0.f;
            const __half2* e2a = (const __half2*)&we0;
            const __half2* e2b = (const __half2*)&we1;
            const __half2* a2a = (const __half2*)&wa0;
            const __half2* a2b = (const __half2*)&wa1;
            #pragma unroll
            for (int d = 0; d < 4; ++d) {
                float h0v = hnew[j + 16*(2*d)], h1v = hnew[j + 16*(2*d+1)];
                float2 pe = __half22float2(e2a[d]);
                float2 pa = __half22float2(a2a[d]);
                se += pe.x*h0v + pe.y*h1v;
                sa += pa.x*h0v + pa.y*h1v;
            }
            #pragma unroll
            for (int d = 0; d < 4; ++d) {
                float h0v = hnew[j + 16*(8+2*d)], h1v = hnew[j + 16*(8+2*d+1)];
                float2 pe = __half22float2(e2b[d]);
                float2 pa = __half22float2(a2b[d]);
                se += pe.x*h0v + pe.y*h1v;
                sa += pa.x*h0v + pa.y*h1v;
            }
            se += __shfl_down(se, 8, 16); sa += __shfl_down(sa, 8, 16);
            se += __shfl_down(se, 4, 16); sa += __shfl_down(sa, 4, 16);
            se += __shfl_down(se, 2, 16); sa += __shfl_down(sa, 2, 16);
            se += __shfl_down(se, 1, 16); sa += __shfl_down(sa, 1, 16);
            if (j == 0) {
                float e = 1.f/(1.f + expf(-se));
                float a = tanhf(sa);
                sE[m] = e; sA[m] = a;
                eag[(size_t)(b*16 + t)*80 + m]      = e;
                eag[(size_t)(b*16 + t)*80 + 32 + m] = a;
            }
            // g (redundant per wave)
            float4 h4 = *(const float4*)&hnew[lane*4];
            float p = wg4.x*h4.x + wg4.y*h4.y + wg4.z*h4.z + wg4.w*h4.w;
            #pragma unroll
            for (int d = 32; d > 0; d >>= 1) p += __shfl_xor(p, d, 64);
            gg = 1.f/(1.f + expf(-p));
            if (tid == 0) eag[(size_t)(b*16 + t)*80 + 64] = gg;
        }
        __syncthreads();   // bar4: sE/sA ready

        // ---- P4b: c update in registers (x from f16 transposed copy); no trailing barrier
        {
            float omg = 1.f - gg;
            uint4 xbv[8];
            const uint4* xrow = (const uint4*)(xh + (size_t)(b*16 + t)*32768) + 8*tid;
            #pragma unroll
            for (int i = 0; i < 8; ++i) xbv[i] = xrow[i];
            const __half* xp = (const __half*)xbv;
            #pragma unroll
            for (int q = 0; q < 8; ++q) {
                float4 e4 = *(const float4*)&sE[4*q];
                float4 a4 = *(const float4*)&sA[4*q];
                #pragma unroll
                for (int r = 0; r < 4; ++r) {
                    int m = 4*q + r;
                    float e = (r==0)?e4.x:(r==1)?e4.y:(r==2)?e4.z:e4.w;
                    float a = (r==0)?a4.x:(r==1)?a4.y:(r==2)?a4.z:a4.w;
                    float x0v = __half2float(xp[m]);
                    float x1v = __half2float(xp[32 + m]);
                    c0[m] = omg*(c0[m]*(1.f - w0*e) + w0*a) + gg*x0v;
                    c1[m] = omg*(c1[m]*(1.f - w1*e) + w1*a) + gg*x1v;
                }
            }
        }
    }
}

// ---------------- replay: reconstruct cseq from scalars, fully parallel
__global__ __launch_bounds__(256) void ntm_replay_kernel(
    const float* __restrict__ xfeat, const float* __restrict__ wbuf,
    const float* __restrict__ eag, const float* __restrict__ lnst,
    float* __restrict__ cseq)
{
    const int slab = blockIdx.x;    // 16 slabs of 64 n
    const int b    = blockIdx.y;    // 8
    const int tid  = threadIdx.x;
    const int m    = tid >> 3;      // 32
    const int ns   = tid & 7;       // 8 subgroups of 8 n
    const int n0   = slab*64 + ns*8;
    const float mu = lnst[b*2], rs = lnst[b*2+1];

    float c[8];
    {
        const float* x0 = xfeat + (size_t)(b*16)*32768 + m*1024 + n0;
        float4 a = *(const float4*)x0;
        float4 bv = *(const float4*)(x0 + 4);
        c[0]=(a.x-mu)*rs; c[1]=(a.y-mu)*rs; c[2]=(a.z-mu)*rs; c[3]=(a.w-mu)*rs;
        c[4]=(bv.x-mu)*rs; c[5]=(bv.y-mu)*rs; c[6]=(bv.z-mu)*rs; c[7]=(bv.w-mu)*rs;
    }
    for (int t = 0; t < 16; ++t) {
        const size_t bt = (size_t)(b*16 + t);
        const float* wp = &wbuf[bt*1024 + n0];
        float4 wA = *(const float4*)wp;
        float4 wB = *(const float4*)(wp + 4);
        float e = eag[bt*80 + m];
        float a = eag[bt*80 + 32 + m];
        float g = eag[bt*80 + 64];
        float omg = 1.f - g;
        const float* xp = &xfeat[bt*32768 + m*1024 + n0];
        float4 xA = *(const float4*)xp;
        float4 xB = *(const float4*)(xp + 4);
        c[0] = omg*(c[0]*(1.f - wA.x*e) + wA.x*a) + g*xA.x;
        c[1] = omg*(c[1]*(1.f - wA.y*e) + wA.y*a) + g*xA.y;
        c[2] = omg*(c[2]*(1.f - wA.z*e) + wA.z*a) + g*xA.z;
        c[3] = omg*(c[3]*(1.f - wA.w*e) + wA.w*a) + g*xA.w;
        c[4] = omg*(c[4]*(1.f - wB.x*e) + wB.x*a) + g*xB.x;
        c[5] = omg*(c[5]*(1.f - wB.y*e) + wB.y*a) + g*xB.y;
        c[6] = omg*(c[6]*(1.f - wB.z*e) + wB.z*a) + g*xB.z;
        c[7] = omg*(c[7]*(1.f - wB.w*e) + wB.w*a) + g*xB.w;
        float* op = &cseq[bt*32768 + m*1024 + n0];
        *(float4*)op       = make_float4(c[0], c[1], c[2], c[3]);
        *(float4*)(op + 4) = make_float4(c[4], c[5], c[6], c[7]);
    }
}

// ---------------- rfft2 of 32x32 windowed tile via 2-stage DFT; one block per (bt,m) image
__global__ __launch_bounds__(256) void fft_fwd_kernel(const float* __restrict__ src,
                                                      const float* __restrict__ cosw,
                                                      float* __restrict__ dst)
{
    const int img = blockIdx.x;
    const int tid = threadIdx.x;
    __shared__ float sY[1024];
    __shared__ float sR[32*17*2];
    __shared__ float ct[32], st[32];
    if (tid < 32) {
        float sv, cv;
        sincosf(TWOPI_32 * (float)tid, &sv, &cv);
        ct[tid] = cv; st[tid] = sv;
    }
    {
        float4 v = *(const float4*)&src[(size_t)img*1024 + tid*4];
        float4 c = *(const float4*)&cosw[tid*4];
        float4 o; o.x = v.x*c.x; o.y = v.y*c.y; o.z = v.z*c.z; o.w = v.w*c.w;
        *(float4*)&sY[tid*4] = o;
    }
    __syncthreads();
    // stage 1: rfft along w: R[h][k] = sum_w y e^{-2pi i w k/32}
    for (int idx = tid; idx < 544; idx += 256) {
        int h = idx / 17;
        int k = idx - h*17;
        const float* y = &sY[h*32];
        float re = 0.f, im = 0.f;
        #pragma unroll
        for (int wq = 0; wq < 32; ++wq) {
            int a = (wq*k) & 31;
            re += y[wq] * ct[a];
            im -= y[wq] * st[a];
        }
        sR[idx*2] = re; sR[idx*2+1] = im;
    }
    __syncthreads();
    // stage 2: full fft along h
    for (int idx = tid; idx < 544; idx += 256) {
        int j = idx / 17;
        int k = idx - j*17;
        float re = 0.f, im = 0.f;
        #pragma unroll
        for (int h = 0; h < 32; ++h) {
            float ar = sR[(h*17+k)*2], ai = sR[(h*17+k)*2+1];
            int a = (h*j) & 31;
            float c = ct[a], s = st[a];
            re += ar*c + ai*s;
            im += ai*c - ar*s;
        }
        dst[((size_t)img*544 + idx)*2]     = re;
        dst[((size_t)img*544 + idx)*2 + 1] = im;
    }
}

// ---------------- channel-sum DCF combine (parallel: 1 thread per (bt,idx))
__global__ __launch_bounds__(256) void combine_kernel(const float* __restrict__ cfft,
                                                      const float* __restrict__ zfft,
                                                      const float* __restrict__ yf,
                                                      float* __restrict__ rfreq)
{
    int gid = blockIdx.x*256 + threadIdx.x;
    if (gid >= 128*544) return;
    int bt  = gid / 544;
    int idx = gid - bt*544;
    float kzz = 0.f, kxr = 0.f, kxi = 0.f;
    #pragma unroll 4
    for (int m = 0; m < 32; ++m) {
        size_t base = ((size_t)(bt*32 + m)*544 + idx)*2;
        float2 c = *(const float2*)&cfft[base];
        float2 z = *(const float2*)&zfft[base];
        kzz += c.x*c.x + c.y*c.y;
        kxr += z.x*c.x + z.y*c.y;   // z * conj(c)
        kxi += z.y*c.x - z.x*c.y;
    }
    float den = 1.f / (kzz + 1e-4f);
    float2 y = *(const float2*)&yf[idx*2];
    float ar = y.x*den, ai = y.y*den;
    *(float2*)&rfreq[(size_t)gid*2] = make_float2(kxr*ar - kxi*ai, kxr*ai + kxi*ar);
}

// ---------------- irfft2 back to 32x32 real response; one block per bt
__global__ __launch_bounds__(256) void ifft_kernel(const float* __restrict__ rfreq,
                                                   float* __restrict__ out)
{
    const int bt  = blockIdx.x;
    const int tid = threadIdx.x;
    __shared__ float sG[544*2];
    __shared__ float sS[544*2];
    __shared__ float ct[32], st[32];
    if (tid < 32) {
        float sv, cv;
        sincosf(TWOPI_32 * (float)tid, &sv, &cv);
        ct[tid] = cv; st[tid] = sv;
    }
    for (int i = tid; i < 1088; i += 256) sG[i] = rfreq[(size_t)bt*1088 + i];
    __syncthreads();
    // stage 1: inverse fft along j
    for (int idx = tid; idx < 544; idx += 256) {
        int h = idx / 17;
        int k = idx - h*17;
        float re = 0.f, im = 0.f;
        #pragma unroll
        for (int j = 0; j < 32; ++j) {
            float gr = sG[(j*17+k)*2], gi = sG[(j*17+k)*2+1];
            int a = (h*j) & 31;
            float c = ct[a], s = st[a];
            re += gr*c - gi*s;
            im += gr*s + gi*c;
        }
        sS[(h*17+k)*2] = re; sS[(h*17+k)*2+1] = im;
    }
    __syncthreads();
    // stage 2: inverse rfft along w with hermitian extension; scale 1/1024
    #pragma unroll
    for (int p = 0; p < 4; ++p) {
        int pos = p*256 + tid;
        int h = pos >> 5, wq = pos & 31;
        float acc = sS[(h*17)*2];
        #pragma unroll
        for (int k = 1; k < 16; ++k) {
            int a = (wq*k) & 31;
            acc += 2.f*(sS[(h*17+k)*2]*ct[a] - sS[(h*17+k)*2+1]*st[a]);
        }
        acc += sS[(h*17+16)*2] * ((wq & 1) ? -1.f : 1.f);
        out[(size_t)bt*1024 + pos] = acc * (1.f/1024.f);
    }
}

extern "C" void kernel_launch(void* const* d_in, const int* in_sizes, int n_in,
                              void* d_out, int out_size, void* d_ws, size_t ws_size,
                              hipStream_t stream)
{
    const float* x_i   = (const float*)d_in[0];
    const float* z_i   = (const float*)d_in[1];
    const float* c1w   = (const float*)d_in[2];
    const float* c1b   = (const float*)d_in[3];
    const float* c2w   = (const float*)d_in[4];
    const float* c2b   = (const float*)d_in[5];
    const float* Wk    = (const float*)d_in[6];
    const float* bk    = (const float*)d_in[7];
    const float* Wbeta = (const float*)d_in[8];
    const float* bbeta = (const float*)d_in[9];
    const float* Wh    = (const float*)d_in[10];
    const float* bh    = (const float*)d_in[11];
    const float* We    = (const float*)d_in[12];
    const float* Wa    = (const float*)d_in[13];
    const float* Wg    = (const float*)d_in[14];
    const float* cosw  = (const float*)d_in[15];
    const float* yf    = (const float*)d_in[16];
    float* out = (float*)d_out;
    float* ws  = (float*)d_ws;

    // workspace layout (floats); peak ~118 MB (unchanged footprint)
    float*  buf1  = ws;                 // conv1 out (16,777,216 f); reused after convs
    float*  xfeat = ws + 16777216;      // 4,194,304
    float*  zfeat = ws + 20971520;      // 4,194,304
    float*  cseq  = ws + 25165824;      // 4,194,304
    float*  rfreq = ws + 29360128;      // 139,264
    float*  xmb   = ws + 29499392;      // 4,096
    // regions inside buf1, valid after conv stage completes:
    float*  cfft  = buf1;               // 4,456,448 f
    float*  zfft  = buf1 + 4456448;     // 4,456,448 f (ends 8,912,896)
    __half* xhb   = (__half*)(ws + 9000000);    // 4,194,304 halfs
    float*  wbuf  = ws + 11100000;      // 131,072 f
    float*  eag   = ws + 11240000;      // 10,240 f
    float*  lnstp = ws + 11251000;      // 16 f
    __half* whhP  = (__half*)(ws + 11300000);   // 65,536 halfs
    __half* whrxP = (__half*)(ws + 11332768);   // 16,384 halfs
    __half* wkP   = (__half*)(ws + 11340960);   // 8,192 halfs
    __half* weP   = (__half*)(ws + 11345056);   // 8,192 halfs
    __half* waP   = (__half*)(ws + 11349152);   // 8,192 halfs (ends 11,353,248)

    dim3 b256(256);
    conv1_kernel<<<dim3(4,128), b256, 0, stream>>>(x_i, c1w, c1b, buf1);
    conv2_kernel<<<dim3(8,128), b256, 0, stream>>>(buf1, c2w, c2b, xfeat);
    conv1_kernel<<<dim3(4,128), b256, 0, stream>>>(z_i, c1w, c1b, buf1);
    conv2_kernel<<<dim3(8,128), b256, 0, stream>>>(buf1, c2w, c2b, zfeat);
    pack_kernel<<<256, b256, 0, stream>>>(Wh, Wk, We, Wa, whhP, whrxP, wkP, weP, waP);
    xhalf_kernel<<<128, b256, 0, stream>>>(xfeat, xhb);
    xmean_kernel<<<1024, b256, 0, stream>>>(xfeat, xmb);
    ntm_scal_kernel<<<8, 512, 0, stream>>>(xfeat, xhb, xmb, whhP, whrxP, wkP, weP, waP,
                                           bk, Wbeta, bbeta, bh, Wg, wbuf, eag, lnstp);
    ntm_replay_kernel<<<dim3(16,8), b256, 0, stream>>>(xfeat, wbuf, eag, lnstp, cseq);
    fft_fwd_kernel<<<4096, b256, 0, stream>>>(cseq, cosw, cfft);
    fft_fwd_kernel<<<4096, b256, 0, stream>>>(zfeat, cosw, zfft);
    combine_kernel<<<272, b256, 0, stream>>>(cfft, zfft, yf, rfreq);
    ifft_kernel<<<128, b256, 0, stream>>>(rfreq, out);
}